// Round 4
// baseline (401.008 us; speedup 1.0000x reference)
//
#include <hip/hip_runtime.h>
#include <stdint.h>

#define N_ROWS 200000
#define NIMG   500
#define DMETA  24
#define WIDTH  32
#define HID    64
#define DEPTH  20
#define MC     32

// All matmuls computed TRANSPOSED with mfma_f32_32x32x16_bf16:
//   Y^T = W^T @ X^T, weights = A-operand (pre-transposed frag tables),
//   activations = B-operand, outputs column-owned by batch-row m = lane&31.
// Master state h[m][w]: lane l holds h[m=l&31][w = WOFF(l>>5, reg)], 16 f32.
// WOFF(h5,reg) = (reg&3) + 8*(reg>>2) + 4*h5  (the 32x32 C/D row mapping).
// B-frags for the next matmul are built in-register: cvt_pk packs adjacent
// regs (w,w+1); one v_permlane32_swap_b32 per word pair exchanges lane halves
// so each lane holds its full k-range. ZERO LDS in the hot loop.

// ws layout (bytes):
//   [0, 64000)         : sums (500*32 f32), zeroed by prep
//   [WB + l*LSTR2 ...) : per-layer block, l = 0..19 (LSTR2 = 16768):
//       +0     W1^T A-frags [tm(2)][ks(2)][hi/lo(2)][lane(64)][j(8)] bf16
//       +8192  W2^T A-frags [ks2(4)][hi/lo(2)][lane(64)][j(8)] bf16
//       +16384 b1 quads [tm(2)][h5(2)][reg(16)] f32  (= b1[l][32tm+WOFF])
//       +16640 b2 quads [h5(2)][reg(16)] f32         (= b2[l][WOFF])
//   OFF_WI  : wimg^T frags [ks(2)][hi/lo][lane][j] (4096 B)
//   OFF_WS  : wsc^T frags (4096 B)
//   OFF_BIQ : bimg quads [h5][reg] (128 B)
//   OFF_BSQ : bsc quads (128 B)
//   OFF_WOQ : wout quads [h5][reg][2] f32 (256 B)
#define WB      64000
#define LSTR2   16768
#define OFF_WI  (WB + DEPTH * LSTR2)   // 399360
#define OFF_WS  (OFF_WI + 4096)        // 403456
#define OFF_BIQ (OFF_WS + 4096)        // 407552
#define OFF_BSQ (OFF_BIQ + 128)        // 407680
#define OFF_WOQ (OFF_BSQ + 128)        // 407808, end 408064

typedef __attribute__((ext_vector_type(8))) short bf16x8;
typedef __attribute__((ext_vector_type(4))) float f32x4;
typedef __attribute__((ext_vector_type(16))) float f32x16;

#define MFMA32(a, b, acc) __builtin_amdgcn_mfma_f32_32x32x16_bf16((a), (b), (acc), 0, 0, 0)
// vdst upper 32 lanes <-> vsrc lower 32 lanes
#define SWP(x, y) asm("v_permlane32_swap_b32 %0, %1" : "+v"(x), "+v"(y))
#define WOFFi(h5, reg) ((((reg) & 3) + 8 * ((reg) >> 2)) + 4 * (h5))

__device__ __forceinline__ uint32_t rotl32(uint32_t x, int r) {
    return (x << r) | (x >> (32 - r));
}

// JAX partitionable threefry, key (0,42): bits(j) = x0^x1 of threefry2x32((0,42),(0,j))
__device__ __forceinline__ uint32_t tf_bits(uint32_t j) {
    const uint32_t ks1 = 42u, ks2 = 0x1BD11BDAu ^ 42u;
    uint32_t x0 = 0u, x1 = j + ks1;
#define R4(a,b,c,d) \
    x0 += x1; x1 = rotl32(x1,(a)); x1 ^= x0; \
    x0 += x1; x1 = rotl32(x1,(b)); x1 ^= x0; \
    x0 += x1; x1 = rotl32(x1,(c)); x1 ^= x0; \
    x0 += x1; x1 = rotl32(x1,(d)); x1 ^= x0;
    R4(13,15,26,6)  x0 += ks1; x1 += ks2 + 1u;
    R4(17,29,16,24) x0 += ks2; x1 += 0u + 2u;
    R4(13,15,26,6)                x1 += ks1 + 3u;
    R4(17,29,16,24) x0 += ks1; x1 += ks2 + 4u;
    R4(13,15,26,6)  x0 += ks2; x1 += 0u + 5u;
#undef R4
    return x0 ^ x1;
}

__device__ __forceinline__ float bits_to_normal(uint32_t b) {
    float f = __uint_as_float((b >> 9) | 0x3f800000u) - 1.0f;
    const float lo = -0.99999994f;
    float u = fmaxf(lo, f * 2.0f + lo);
    return 1.41421356f * erfinvf(u);
}

// split (prep, scalar): round-half-up hi, truncated lo. |x - hi - lo| <~ 2^-16 |x|
__device__ __forceinline__ void split1(float x, short& hi, short& lo) {
    uint32_t b = __float_as_uint(x);
    uint32_t a = b + 0x8000u;
    hi = (short)(a >> 16);
    float r = x - __uint_as_float(a & 0xFFFF0000u);
    lo = (short)(__float_as_uint(r) >> 16);
}

// vector split+pack: 8 f32 -> bf16x8 hi, bf16x8 lo via v_cvt_pk_bf16_f32
__device__ __forceinline__ void split8p(const float* x, bf16x8& hi, bf16x8& lo) {
    uint32_t hu[4], lu[4];
#pragma unroll
    for (int p = 0; p < 4; ++p) {
        float x0 = x[2 * p], x1 = x[2 * p + 1];
        uint32_t h;
        asm("v_cvt_pk_bf16_f32 %0, %1, %2" : "=v"(h) : "v"(x0), "v"(x1));
        float r0 = x0 - __uint_as_float(h << 16);
        float r1 = x1 - __uint_as_float(h & 0xFFFF0000u);
        uint32_t l;
        asm("v_cvt_pk_bf16_f32 %0, %1, %2" : "=v"(l) : "v"(r0), "v"(r1));
        hu[p] = h;
        lu[p] = l;
    }
    __builtin_memcpy(&hi, hu, 16);
    __builtin_memcpy(&lo, lu, 16);
}

// 20 residual blocks, one 32-row tile per wave, zero LDS.
// Stage 1 (H1^T = W1^T @ h^T): h hi/lo split, weights hi/lo -> 3 terms.
// Stage 2 (delta^T = W2^T @ H1^T): H1 single RNE bf16, weights hi/lo -> 2 terms.
__device__ __forceinline__ void mlp20(float* h, const char* __restrict__ wsb,
                                      int lane, int h5) {
    uint32_t lb = WB;
    const uint32_t lf = (uint32_t)(lane * 16);
#pragma unroll 1
    for (int l = 0; l < DEPTH; ++l) {
        // ---- stage-1 B prep: split h -> hi/lo words, half-swap into B-frags
        uint32_t Hh[8], Hl[8];
#pragma unroll
        for (int p = 0; p < 8; ++p) {
            float x0 = h[2 * p], x1 = h[2 * p + 1];
            uint32_t wd;
            asm("v_cvt_pk_bf16_f32 %0, %1, %2" : "=v"(wd) : "v"(x0), "v"(x1));
            float r0 = x0 - __uint_as_float(wd << 16);
            float r1 = x1 - __uint_as_float(wd & 0xFFFF0000u);
            uint32_t ld;
            asm("v_cvt_pk_bf16_f32 %0, %1, %2" : "=v"(ld) : "v"(r0), "v"(r1));
            Hh[p] = wd;
            Hl[p] = ld;
        }
        SWP(Hh[0], Hh[2]); SWP(Hh[1], Hh[3]); SWP(Hh[4], Hh[6]); SWP(Hh[5], Hh[7]);
        SWP(Hl[0], Hl[2]); SWP(Hl[1], Hl[3]); SWP(Hl[4], Hl[6]); SWP(Hl[5], Hl[7]);
        bf16x8 B0h, B0l, B1h, B1l;
        __builtin_memcpy(&B0h, &Hh[0], 16);
        __builtin_memcpy(&B1h, &Hh[4], 16);
        __builtin_memcpy(&B0l, &Hl[0], 16);
        __builtin_memcpy(&B1l, &Hl[4], 16);
        // ---- stage 1: two M-tiles (u-halves), bias quads as C-init
        uint32_t P[16];
#pragma unroll
        for (int tm = 0; tm < 2; ++tm) {
            f32x16 acc;
            {
                const char* bq = wsb + lb + 16384u + (uint32_t)(tm * 128 + h5 * 64);
#pragma unroll
                for (int r = 0; r < 4; ++r) {
                    f32x4 q = *(const f32x4*)(bq + 16 * r);
#pragma unroll
                    for (int i = 0; i < 4; ++i) acc[4 * r + i] = q[i];
                }
            }
            const char* fa = wsb + lb + lf + (uint32_t)(tm * 4096);
            bf16x8 a0h = *(const bf16x8*)(fa);
            bf16x8 a0l = *(const bf16x8*)(fa + 1024);
            bf16x8 a1h = *(const bf16x8*)(fa + 2048);
            bf16x8 a1l = *(const bf16x8*)(fa + 3072);
            acc = MFMA32(a0h, B0h, acc);
            acc = MFMA32(a0h, B0l, acc);
            acc = MFMA32(a0l, B0h, acc);
            acc = MFMA32(a1h, B1h, acc);
            acc = MFMA32(a1h, B1l, acc);
            acc = MFMA32(a1l, B1h, acc);
            // relu + pack to bf16 words (u-pairs)
#pragma unroll
            for (int p = 0; p < 8; ++p) {
                float f0 = fmaxf(acc[2 * p], 0.0f);
                float f1 = fmaxf(acc[2 * p + 1], 0.0f);
                uint32_t wd;
                asm("v_cvt_pk_bf16_f32 %0, %1, %2" : "=v"(wd) : "v"(f0), "v"(f1));
                P[tm * 8 + p] = wd;
            }
        }
        // half-swap into stage-2 B-frags (4 K-steps over u=0..63)
        SWP(P[0], P[2]);  SWP(P[1], P[3]);  SWP(P[4], P[6]);   SWP(P[5], P[7]);
        SWP(P[8], P[10]); SWP(P[9], P[11]); SWP(P[12], P[14]); SWP(P[13], P[15]);
        // ---- stage 2: acc init = h + b2 quad (residual in-register)
        f32x16 acc2;
        {
            const char* bq = wsb + lb + 16640u + (uint32_t)(h5 * 64);
#pragma unroll
            for (int r = 0; r < 4; ++r) {
                f32x4 q = *(const f32x4*)(bq + 16 * r);
#pragma unroll
                for (int i = 0; i < 4; ++i) acc2[4 * r + i] = h[4 * r + i] + q[i];
            }
        }
#pragma unroll
        for (int ks = 0; ks < 4; ++ks) {
            bf16x8 Bk;
            __builtin_memcpy(&Bk, &P[ks * 4], 16);
            const char* fa = wsb + lb + lf + 8192u + (uint32_t)(ks * 2048);
            bf16x8 ah = *(const bf16x8*)(fa);
            bf16x8 al = *(const bf16x8*)(fa + 1024);
            acc2 = MFMA32(ah, Bk, acc2);
            acc2 = MFMA32(al, Bk, acc2);
        }
#pragma unroll
        for (int i = 0; i < 16; ++i) h[i] = acc2[i];
        lb += LSTR2;
    }
}

// transposed input projection: h0^T = Wimg^T @ X^T (K=32, 2 K-steps, 6 MFMA)
__device__ __forceinline__ void input_proj32(
    const bf16x8& x0h, const bf16x8& x0l, const bf16x8& x1h, const bf16x8& x1l,
    const char* __restrict__ wsb, uint32_t wfoff, uint32_t bqoff,
    float* h, int lane, int h5) {
    f32x16 acc;
    {
        const char* bq = wsb + bqoff + (uint32_t)(h5 * 64);
#pragma unroll
        for (int r = 0; r < 4; ++r) {
            f32x4 q = *(const f32x4*)(bq + 16 * r);
#pragma unroll
            for (int i = 0; i < 4; ++i) acc[4 * r + i] = q[i];
        }
    }
    const char* fa = wsb + wfoff + (uint32_t)(lane * 16);
    bf16x8 a0h = *(const bf16x8*)(fa);
    bf16x8 a0l = *(const bf16x8*)(fa + 1024);
    bf16x8 a1h = *(const bf16x8*)(fa + 2048);
    bf16x8 a1l = *(const bf16x8*)(fa + 3072);
    acc = MFMA32(a0h, x0h, acc);
    acc = MFMA32(a0h, x0l, acc);
    acc = MFMA32(a0l, x0h, acc);
    acc = MFMA32(a1h, x1h, acc);
    acc = MFMA32(a1h, x1l, acc);
    acc = MFMA32(a1l, x1h, acc);
#pragma unroll
    for (int i = 0; i < 16; ++i) h[i] = acc[i];
}

// load X^T B-frags for row = R + (lane&31): ks0 covers d=8h5..8h5+7 (md),
// ks1 covers d=16+8h5..23/24..31 (md / iobs,sig,pad)
__device__ __forceinline__ void load_xfrags(
    const float* __restrict__ md, const float* __restrict__ iobs,
    const float* __restrict__ sig, int row, int h5,
    bf16x8& x0h, bf16x8& x0l, bf16x8& x1h, bf16x8& x1l) {
    float xa0[8], xa1[8];
    {
        const f32x4* rp = (const f32x4*)(md + (size_t)row * DMETA + 8 * h5);
        f32x4 a = rp[0], b = rp[1];
#pragma unroll
        for (int j = 0; j < 4; ++j) { xa0[j] = a[j]; xa0[4 + j] = b[j]; }
    }
    if (h5 == 0) {
        const f32x4* rp = (const f32x4*)(md + (size_t)row * DMETA + 16);
        f32x4 a = rp[0], b = rp[1];
#pragma unroll
        for (int j = 0; j < 4; ++j) { xa1[j] = a[j]; xa1[4 + j] = b[j]; }
    } else {
        xa1[0] = iobs ? iobs[row] : 0.0f;
        xa1[1] = sig ? sig[row] : 0.0f;
#pragma unroll
        for (int j = 2; j < 8; ++j) xa1[j] = 0.0f;
    }
    split8p(xa0, x0h, x0l);
    split8p(xa1, x1h, x1l);
}

// prep: zero sums; transposed frag tables + bias/wout quads
__global__ __launch_bounds__(256) void prep_kernel(
    const float* __restrict__ w1, const float* __restrict__ w2,
    const float* __restrict__ wimg, const float* __restrict__ wsc,
    const float* __restrict__ b1, const float* __restrict__ b2,
    const float* __restrict__ bimg, const float* __restrict__ bsc,
    const float* __restrict__ wout, char* __restrict__ wsb) {
    int t = blockIdx.x * 256 + threadIdx.x;
    float* sums = (float*)wsb;
    if (t < 16000) { sums[t] = 0.0f; return; }
    t -= 16000;
    if (t < 40960) {  // W1^T frags: A[u][k] = W1[k][u]
        int l = t >> 11, r = t & 2047;
        int tm = r >> 10, ks = (r >> 9) & 1, lane = (r >> 3) & 63, j = r & 7;
        int k = 16 * ks + 8 * (lane >> 5) + j;
        int u = 32 * tm + (lane & 31);
        short hh, ll;
        split1(w1[l * 2048 + k * 64 + u], hh, ll);
        char* base = wsb + WB + l * LSTR2 + (tm * 2 + ks) * 2048 + 2 * (lane * 8 + j);
        *(short*)base = hh;
        *(short*)(base + 1024) = ll;
        return;
    }
    t -= 40960;
    if (t < 40960) {  // W2^T frags: A[w][u] = W2[u][w]
        int l = t >> 11, r = t & 2047;
        int ks = r >> 9, lane = (r >> 3) & 63, j = r & 7;
        int u = 16 * ks + 8 * (lane >> 5) + j;
        int w = lane & 31;
        short hh, ll;
        split1(w2[l * 2048 + u * 32 + w], hh, ll);
        char* base = wsb + WB + l * LSTR2 + 8192 + ks * 2048 + 2 * (lane * 8 + j);
        *(short*)base = hh;
        *(short*)(base + 1024) = ll;
        return;
    }
    t -= 40960;
    if (t < 1280) {  // b1 quads [l][tm][h5][reg]
        int l = t >> 6, r = t & 63;
        int tm = r >> 5, h5 = (r >> 4) & 1, reg = r & 15;
        *(float*)(wsb + WB + l * LSTR2 + 16384 + tm * 128 + h5 * 64 + reg * 4) =
            b1[l * 64 + 32 * tm + WOFFi(h5, reg)];
        return;
    }
    t -= 1280;
    if (t < 640) {  // b2 quads [l][h5][reg]
        int l = t >> 5, r = t & 31;
        int h5 = r >> 4, reg = r & 15;
        *(float*)(wsb + WB + l * LSTR2 + 16640 + h5 * 64 + reg * 4) =
            b2[l * 32 + WOFFi(h5, reg)];
        return;
    }
    t -= 640;
    if (t < 1024) {  // wimg^T frags (d padded 26->32)
        int ks = t >> 9, lane = (t >> 3) & 63, j = t & 7;
        int d = 16 * ks + 8 * (lane >> 5) + j, w = lane & 31;
        float v = (d < 26) ? wimg[d * 32 + w] : 0.0f;
        short hh, ll;
        split1(v, hh, ll);
        char* base = wsb + OFF_WI + ks * 2048 + 2 * (lane * 8 + j);
        *(short*)base = hh;
        *(short*)(base + 1024) = ll;
        return;
    }
    t -= 1024;
    if (t < 1024) {  // wsc^T frags (d padded 24->32)
        int ks = t >> 9, lane = (t >> 3) & 63, j = t & 7;
        int d = 16 * ks + 8 * (lane >> 5) + j, w = lane & 31;
        float v = (d < 24) ? wsc[d * 32 + w] : 0.0f;
        short hh, ll;
        split1(v, hh, ll);
        char* base = wsb + OFF_WS + ks * 2048 + 2 * (lane * 8 + j);
        *(short*)base = hh;
        *(short*)(base + 1024) = ll;
        return;
    }
    t -= 1024;
    if (t < 32) {  // bimg quads
        int h5 = t >> 4, reg = t & 15;
        *(float*)(wsb + OFF_BIQ + h5 * 64 + reg * 4) = bimg[WOFFi(h5, reg)];
        return;
    }
    t -= 32;
    if (t < 32) {  // bsc quads
        int h5 = t >> 4, reg = t & 15;
        *(float*)(wsb + OFF_BSQ + h5 * 64 + reg * 4) = bsc[WOFFi(h5, reg)];
        return;
    }
    t -= 32;
    if (t < 64) {  // wout quads [h5][reg][2]
        int h5 = t >> 5, r = t & 31, reg = r >> 1, comp = r & 1;
        *(float*)(wsb + OFF_WOQ + h5 * 128 + reg * 8 + comp * 4) =
            wout[WOFFi(h5, reg) * 2 + comp];
        return;
    }
}

// pass A: input proj -> mlp20 -> segment-sum
__global__ __launch_bounds__(128, 4) void pass_a(
    const float* __restrict__ md, const float* __restrict__ iobs,
    const float* __restrict__ sig, const char* __restrict__ wsb,
    const int* __restrict__ ids, float* __restrict__ sums) {
    int lane = threadIdx.x & 63, wv = threadIdx.x >> 6;
    int h5 = lane >> 5;
    int R = (blockIdx.x * 2 + wv) * 32;
    int row = R + (lane & 31);

    bf16x8 x0h, x0l, x1h, x1l;
    load_xfrags(md, iobs, sig, row, h5, x0h, x0l, x1h, x1l);

    float h[16];
    input_proj32(x0h, x0l, x1h, x1l, wsb, OFF_WI, OFF_BIQ, h, lane, h5);
    mlp20(h, wsb, lane, h5);

    int id0 = ids[R];
    bool uni = (id0 == ids[R + 31]);
    if (uni) {
#pragma unroll
        for (int m = 1; m < 32; m <<= 1) {
#pragma unroll
            for (int i = 0; i < 16; ++i) h[i] += __shfl_xor(h[i], m, 64);
        }
        if ((lane & 31) == 0) {
#pragma unroll
            for (int i = 0; i < 16; ++i)
                atomicAdd(&sums[id0 * 32 + WOFFi(h5, i)], h[i]);
        }
    } else {
        int id = ids[row];
#pragma unroll
        for (int i = 0; i < 16; ++i)
            atomicAdd(&sums[id * 32 + WOFFi(h5, i)], h[i]);
    }
}

__global__ __launch_bounds__(256) void normalize_kernel(float* __restrict__ sums,
                                                        const int* __restrict__ cnts) {
    int t = blockIdx.x * 256 + threadIdx.x;
    if (t < NIMG * WIDTH) {
        int img = t >> 5;
        float cc = (float)max(cnts[img], 1);
        sums[t] = sums[t] / cc;
    }
}

// pass B: input proj + pooled -> mlp20 -> head -> sample -> z, kl
__global__ __launch_bounds__(128, 4) void pass_b(
    const float* __restrict__ md, const char* __restrict__ wsb,
    const float* __restrict__ bout, const int* __restrict__ ids,
    const float* __restrict__ pooled, float* __restrict__ out) {
    int lane = threadIdx.x & 63, wv = threadIdx.x >> 6;
    int h5 = lane >> 5;
    int R = (blockIdx.x * 2 + wv) * 32;
    int row = R + (lane & 31);

    bf16x8 x0h, x0l, x1h, x1l;
    load_xfrags(md, nullptr, nullptr, row, h5, x0h, x0l, x1h, x1l);

    float h[16];
    input_proj32(x0h, x0l, x1h, x1l, wsb, OFF_WS, OFF_BSQ, h, lane, h5);

    // add pooled[id][w] (pooled row layout matches WOFF quads)
    {
        int idp = ids[row];
#pragma unroll
        for (int a = 0; a < 4; ++a) {
            f32x4 q = *(const f32x4*)(pooled + idp * 32 + 8 * a + 4 * h5);
#pragma unroll
            for (int i = 0; i < 4; ++i) h[4 * a + i] += q[i];
        }
    }

    mlp20(h, wsb, lane, h5);

    // head: params[m] = h[m] @ wout + bout; lane-local partial + one xor32
    float p0 = 0.0f, p1 = 0.0f;
    {
        const char* wq = wsb + OFF_WOQ + (uint32_t)(h5 * 128);
#pragma unroll
        for (int r = 0; r < 8; ++r) {
            f32x4 q = *(const f32x4*)(wq + 16 * r);   // regs 2r, 2r+1 (float2 each)
            p0 = fmaf(h[2 * r], q[0], p0);
            p1 = fmaf(h[2 * r], q[1], p1);
            p0 = fmaf(h[2 * r + 1], q[2], p0);
            p1 = fmaf(h[2 * r + 1], q[3], p1);
        }
    }
    p0 += __shfl_xor(p0, 32, 64);
    p1 += __shfl_xor(p1, 32, 64);
    float loc = p0 + bout[0];
    float pb = p1 + bout[1];
    float scale = fmaxf(pb, 0.0f) + log1pf(expf(-fabsf(pb))) + 1e-12f;
    float lsg = logf(scale);

    // sampling: lane covers its row; half h5 draws samples 16*h5..16*h5+15
    float kp = 0.0f;
    float* zrow = out + (size_t)row * MC + h5 * 16;
#pragma unroll 4
    for (int s4 = 0; s4 < 4; ++s4) {
        f32x4 zv;
#pragma unroll
        for (int jj = 0; jj < 4; ++jj) {
            int tt = h5 * 16 + s4 * 4 + jj;
            uint32_t j = (uint32_t)(tt * N_ROWS) + (uint32_t)row;
            float n = bits_to_normal(tf_bits(j));
            float z = fmaf(scale, n, loc);
            zv[jj] = z;
            kp += fmaf(-0.5f, n * n, fabsf(z));
        }
        *(f32x4*)(zrow + s4 * 4) = zv;
    }
    kp += __shfl_xor(kp, 32, 64);
    if (h5 == 0) {
        out[(size_t)N_ROWS * MC + row] =
            0.01f * (kp * (1.0f / 32.0f) - lsg - 0.91893853320467274f + 0.69314718055994531f);
    }
}

extern "C" void kernel_launch(void* const* d_in, const int* in_sizes, int n_in,
                              void* d_out, int out_size, void* d_ws, size_t ws_size,
                              hipStream_t stream) {
    const float* md   = (const float*)d_in[0];
    const float* iobs = (const float*)d_in[1];
    const float* sig  = (const float*)d_in[2];
    const float* wimg = (const float*)d_in[3];
    const float* bimg = (const float*)d_in[4];
    const float* wsc  = (const float*)d_in[5];
    const float* bsc  = (const float*)d_in[6];
    const float* w1   = (const float*)d_in[7];
    const float* b1   = (const float*)d_in[8];
    const float* w2   = (const float*)d_in[9];
    const float* b2   = (const float*)d_in[10];
    const float* wout = (const float*)d_in[11];
    const float* bout = (const float*)d_in[12];
    const int* ids    = (const int*)d_in[13];
    const int* cnts   = (const int*)d_in[14];
    float* out = (float*)d_out;
    char* wsb = (char*)d_ws;
    float* sums = (float*)wsb;

    const int nblk = N_ROWS / 64;  // 3125 blocks x 2 waves x 32 rows, exact
    prep_kernel<<<399, 256, 0, stream>>>(w1, w2, wimg, wsc, b1, b2, bimg, bsc, wout, wsb);
    pass_a<<<nblk, 128, 0, stream>>>(md, iobs, sig, wsb, ids, sums);
    normalize_kernel<<<(NIMG * WIDTH + 255) / 256, 256, 0, stream>>>(sums, cnts);
    pass_b<<<nblk, 128, 0, stream>>>(md, wsb, bout, ids, sums, out);
}

// Round 5
// 391.538 us; speedup vs baseline: 1.0242x; 1.0242x over previous
//
#include <hip/hip_runtime.h>
#include <stdint.h>

#define N_ROWS 200000
#define NIMG   500
#define DMETA  24
#define WIDTH  32
#define HID    64
#define DEPTH  20
#define MC     32

// All matmuls TRANSPOSED with mfma_f32_32x32x16_bf16 (Y^T = W^T @ X^T),
// weights = A-operand (pre-transposed frag tables in ws), activations =
// B-operand. Lane l owns h[m=l&31][w=WOFF(l>>5,reg)]. ZERO LDS in hot loop.
// Each wave runs TWO independent 32-row tiles; weight frags/bias quads are
// loaded once and shared by both tiles (2 independent MFMA chains -> ILP).

// ws layout: identical to round 4.
#define WB      64000
#define LSTR2   16768
#define OFF_WI  (WB + DEPTH * LSTR2)   // 399360
#define OFF_WS  (OFF_WI + 4096)        // 403456
#define OFF_BIQ (OFF_WS + 4096)        // 407552
#define OFF_BSQ (OFF_BIQ + 128)        // 407680
#define OFF_WOQ (OFF_BSQ + 128)        // 407808, end 408064

typedef __attribute__((ext_vector_type(8))) short bf16x8;
typedef __attribute__((ext_vector_type(4))) float f32x4;
typedef __attribute__((ext_vector_type(16))) float f32x16;

#define MFMA32(a, b, acc) __builtin_amdgcn_mfma_f32_32x32x16_bf16((a), (b), (acc), 0, 0, 0)
// vdst upper 32 lanes <-> vsrc lower 32 lanes
#define SWP(x, y) asm("v_permlane32_swap_b32 %0, %1" : "+v"(x), "+v"(y))
#define WOFFi(h5, reg) ((((reg) & 3) + 8 * ((reg) >> 2)) + 4 * (h5))

__device__ __forceinline__ uint32_t rotl32(uint32_t x, int r) {
    return (x << r) | (x >> (32 - r));
}

// JAX partitionable threefry, key (0,42): bits(j) = x0^x1 of threefry2x32((0,42),(0,j))
__device__ __forceinline__ uint32_t tf_bits(uint32_t j) {
    const uint32_t ks1 = 42u, ks2 = 0x1BD11BDAu ^ 42u;
    uint32_t x0 = 0u, x1 = j + ks1;
#define R4(a,b,c,d) \
    x0 += x1; x1 = rotl32(x1,(a)); x1 ^= x0; \
    x0 += x1; x1 = rotl32(x1,(b)); x1 ^= x0; \
    x0 += x1; x1 = rotl32(x1,(c)); x1 ^= x0; \
    x0 += x1; x1 = rotl32(x1,(d)); x1 ^= x0;
    R4(13,15,26,6)  x0 += ks1; x1 += ks2 + 1u;
    R4(17,29,16,24) x0 += ks2; x1 += 0u + 2u;
    R4(13,15,26,6)                x1 += ks1 + 3u;
    R4(17,29,16,24) x0 += ks1; x1 += ks2 + 4u;
    R4(13,15,26,6)  x0 += ks2; x1 += 0u + 5u;
#undef R4
    return x0 ^ x1;
}

__device__ __forceinline__ float bits_to_normal(uint32_t b) {
    float f = __uint_as_float((b >> 9) | 0x3f800000u) - 1.0f;
    const float lo = -0.99999994f;
    float u = fmaxf(lo, f * 2.0f + lo);
    return 1.41421356f * erfinvf(u);
}

// split (prep, scalar): round-half-up hi, truncated lo. |x - hi - lo| <~ 2^-16 |x|
__device__ __forceinline__ void split1(float x, short& hi, short& lo) {
    uint32_t b = __float_as_uint(x);
    uint32_t a = b + 0x8000u;
    hi = (short)(a >> 16);
    float r = x - __uint_as_float(a & 0xFFFF0000u);
    lo = (short)(__float_as_uint(r) >> 16);
}

// vector split+pack: 8 f32 -> bf16x8 hi, bf16x8 lo via v_cvt_pk_bf16_f32
__device__ __forceinline__ void split8p(const float* x, bf16x8& hi, bf16x8& lo) {
    uint32_t hu[4], lu[4];
#pragma unroll
    for (int p = 0; p < 4; ++p) {
        float x0 = x[2 * p], x1 = x[2 * p + 1];
        uint32_t h;
        asm("v_cvt_pk_bf16_f32 %0, %1, %2" : "=v"(h) : "v"(x0), "v"(x1));
        float r0 = x0 - __uint_as_float(h << 16);
        float r1 = x1 - __uint_as_float(h & 0xFFFF0000u);
        uint32_t l;
        asm("v_cvt_pk_bf16_f32 %0, %1, %2" : "=v"(l) : "v"(r0), "v"(r1));
        hu[p] = h;
        lu[p] = l;
    }
    __builtin_memcpy(&hi, hu, 16);
    __builtin_memcpy(&lo, lu, 16);
}

// build stage-1 B-frags for one tile: split h -> hi/lo words + half-swap
__device__ __forceinline__ void mkbfrag(const float* h, bf16x8* Bh, bf16x8* Bl) {
    uint32_t Hh[8], Hl[8];
#pragma unroll
    for (int p = 0; p < 8; ++p) {
        float x0 = h[2 * p], x1 = h[2 * p + 1];
        uint32_t wd;
        asm("v_cvt_pk_bf16_f32 %0, %1, %2" : "=v"(wd) : "v"(x0), "v"(x1));
        float r0 = x0 - __uint_as_float(wd << 16);
        float r1 = x1 - __uint_as_float(wd & 0xFFFF0000u);
        uint32_t ld;
        asm("v_cvt_pk_bf16_f32 %0, %1, %2" : "=v"(ld) : "v"(r0), "v"(r1));
        Hh[p] = wd;
        Hl[p] = ld;
    }
    SWP(Hh[0], Hh[2]); SWP(Hh[1], Hh[3]); SWP(Hh[4], Hh[6]); SWP(Hh[5], Hh[7]);
    SWP(Hl[0], Hl[2]); SWP(Hl[1], Hl[3]); SWP(Hl[4], Hl[6]); SWP(Hl[5], Hl[7]);
    __builtin_memcpy(&Bh[0], &Hh[0], 16);
    __builtin_memcpy(&Bh[1], &Hh[4], 16);
    __builtin_memcpy(&Bl[0], &Hl[0], 16);
    __builtin_memcpy(&Bl[1], &Hl[4], 16);
}

// 20 residual blocks, TWO independent 32-row tiles per wave, zero LDS.
// Weight frags + bias quads loaded once, shared by both tiles' MFMA chains.
__device__ __forceinline__ void mlp20_x2(float* h0, float* h1,
                                         const char* __restrict__ wsb,
                                         int lane, int h5) {
    uint32_t lb = WB;
    const uint32_t lf = (uint32_t)(lane * 16);
#pragma unroll 1
    for (int l = 0; l < DEPTH; ++l) {
        // ---- stage-1 B prep (both tiles; independent -> ILP)
        bf16x8 B0h[2], B0l[2], B1h[2], B1l[2];
        mkbfrag(h0, B0h, B0l);
        mkbfrag(h1, B1h, B1l);
        // ---- stage 1: two M-tiles (u-halves), bias quads as C-init
        uint32_t P0[16], P1[16];
#pragma unroll
        for (int tm = 0; tm < 2; ++tm) {
            f32x16 acc0, acc1;
            {
                const char* bq = wsb + lb + 16384u + (uint32_t)(tm * 128 + h5 * 64);
#pragma unroll
                for (int r = 0; r < 4; ++r) {
                    f32x4 q = *(const f32x4*)(bq + 16 * r);
#pragma unroll
                    for (int i = 0; i < 4; ++i) {
                        acc0[4 * r + i] = q[i];
                        acc1[4 * r + i] = q[i];
                    }
                }
            }
            const char* fa = wsb + lb + lf + (uint32_t)(tm * 4096);
            bf16x8 a0h = *(const bf16x8*)(fa);
            bf16x8 a0l = *(const bf16x8*)(fa + 1024);
            bf16x8 a1h = *(const bf16x8*)(fa + 2048);
            bf16x8 a1l = *(const bf16x8*)(fa + 3072);
            acc0 = MFMA32(a0h, B0h[0], acc0);
            acc1 = MFMA32(a0h, B1h[0], acc1);
            acc0 = MFMA32(a0h, B0l[0], acc0);
            acc1 = MFMA32(a0h, B1l[0], acc1);
            acc0 = MFMA32(a0l, B0h[0], acc0);
            acc1 = MFMA32(a0l, B1h[0], acc1);
            acc0 = MFMA32(a1h, B0h[1], acc0);
            acc1 = MFMA32(a1h, B1h[1], acc1);
            acc0 = MFMA32(a1h, B0l[1], acc0);
            acc1 = MFMA32(a1h, B1l[1], acc1);
            acc0 = MFMA32(a1l, B0h[1], acc0);
            acc1 = MFMA32(a1l, B1h[1], acc1);
            // relu + pack to bf16 words (u-pairs)
#pragma unroll
            for (int p = 0; p < 8; ++p) {
                float f0 = fmaxf(acc0[2 * p], 0.0f);
                float f1 = fmaxf(acc0[2 * p + 1], 0.0f);
                uint32_t wd;
                asm("v_cvt_pk_bf16_f32 %0, %1, %2" : "=v"(wd) : "v"(f0), "v"(f1));
                P0[tm * 8 + p] = wd;
                float g0 = fmaxf(acc1[2 * p], 0.0f);
                float g1 = fmaxf(acc1[2 * p + 1], 0.0f);
                uint32_t we;
                asm("v_cvt_pk_bf16_f32 %0, %1, %2" : "=v"(we) : "v"(g0), "v"(g1));
                P1[tm * 8 + p] = we;
            }
        }
        // half-swap into stage-2 B-frags (4 K-steps over u=0..63)
        SWP(P0[0], P0[2]);  SWP(P0[1], P0[3]);  SWP(P0[4], P0[6]);   SWP(P0[5], P0[7]);
        SWP(P0[8], P0[10]); SWP(P0[9], P0[11]); SWP(P0[12], P0[14]); SWP(P0[13], P0[15]);
        SWP(P1[0], P1[2]);  SWP(P1[1], P1[3]);  SWP(P1[4], P1[6]);   SWP(P1[5], P1[7]);
        SWP(P1[8], P1[10]); SWP(P1[9], P1[11]); SWP(P1[12], P1[14]); SWP(P1[13], P1[15]);
        // ---- stage 2: acc init = h + b2 quad (residual in-register)
        f32x16 acc20, acc21;
        {
            const char* bq = wsb + lb + 16640u + (uint32_t)(h5 * 64);
#pragma unroll
            for (int r = 0; r < 4; ++r) {
                f32x4 q = *(const f32x4*)(bq + 16 * r);
#pragma unroll
                for (int i = 0; i < 4; ++i) {
                    acc20[4 * r + i] = h0[4 * r + i] + q[i];
                    acc21[4 * r + i] = h1[4 * r + i] + q[i];
                }
            }
        }
#pragma unroll
        for (int ks = 0; ks < 4; ++ks) {
            bf16x8 Bk0, Bk1;
            __builtin_memcpy(&Bk0, &P0[ks * 4], 16);
            __builtin_memcpy(&Bk1, &P1[ks * 4], 16);
            const char* fa = wsb + lb + lf + 8192u + (uint32_t)(ks * 2048);
            bf16x8 ah = *(const bf16x8*)(fa);
            bf16x8 al = *(const bf16x8*)(fa + 1024);
            acc20 = MFMA32(ah, Bk0, acc20);
            acc21 = MFMA32(ah, Bk1, acc21);
            acc20 = MFMA32(al, Bk0, acc20);
            acc21 = MFMA32(al, Bk1, acc21);
        }
#pragma unroll
        for (int i = 0; i < 16; ++i) { h0[i] = acc20[i]; h1[i] = acc21[i]; }
        lb += LSTR2;
    }
}

// transposed input projection for both tiles; weight frags shared
__device__ __forceinline__ void input_proj32_x2(
    const bf16x8* X0, const bf16x8* X1,   // per tile: {x0h,x0l,x1h,x1l}
    const char* __restrict__ wsb, uint32_t wfoff, uint32_t bqoff,
    float* h0, float* h1, int lane, int h5) {
    f32x16 acc0, acc1;
    {
        const char* bq = wsb + bqoff + (uint32_t)(h5 * 64);
#pragma unroll
        for (int r = 0; r < 4; ++r) {
            f32x4 q = *(const f32x4*)(bq + 16 * r);
#pragma unroll
            for (int i = 0; i < 4; ++i) { acc0[4 * r + i] = q[i]; acc1[4 * r + i] = q[i]; }
        }
    }
    const char* fa = wsb + wfoff + (uint32_t)(lane * 16);
    bf16x8 a0h = *(const bf16x8*)(fa);
    bf16x8 a0l = *(const bf16x8*)(fa + 1024);
    bf16x8 a1h = *(const bf16x8*)(fa + 2048);
    bf16x8 a1l = *(const bf16x8*)(fa + 3072);
    acc0 = MFMA32(a0h, X0[0], acc0);
    acc1 = MFMA32(a0h, X1[0], acc1);
    acc0 = MFMA32(a0h, X0[1], acc0);
    acc1 = MFMA32(a0h, X1[1], acc1);
    acc0 = MFMA32(a0l, X0[0], acc0);
    acc1 = MFMA32(a0l, X1[0], acc1);
    acc0 = MFMA32(a1h, X0[2], acc0);
    acc1 = MFMA32(a1h, X1[2], acc1);
    acc0 = MFMA32(a1h, X0[3], acc0);
    acc1 = MFMA32(a1h, X1[3], acc1);
    acc0 = MFMA32(a1l, X0[2], acc0);
    acc1 = MFMA32(a1l, X1[2], acc1);
#pragma unroll
    for (int i = 0; i < 16; ++i) { h0[i] = acc0[i]; h1[i] = acc1[i]; }
}

// load X^T B-frags for row: X = {x0h, x0l, x1h, x1l}
__device__ __forceinline__ void load_xfrags(
    const float* __restrict__ md, const float* __restrict__ iobs,
    const float* __restrict__ sig, int row, int h5, bf16x8* X) {
    float xa0[8], xa1[8];
    {
        const f32x4* rp = (const f32x4*)(md + (size_t)row * DMETA + 8 * h5);
        f32x4 a = rp[0], b = rp[1];
#pragma unroll
        for (int j = 0; j < 4; ++j) { xa0[j] = a[j]; xa0[4 + j] = b[j]; }
    }
    if (h5 == 0) {
        const f32x4* rp = (const f32x4*)(md + (size_t)row * DMETA + 16);
        f32x4 a = rp[0], b = rp[1];
#pragma unroll
        for (int j = 0; j < 4; ++j) { xa1[j] = a[j]; xa1[4 + j] = b[j]; }
    } else {
        xa1[0] = iobs ? iobs[row] : 0.0f;
        xa1[1] = sig ? sig[row] : 0.0f;
#pragma unroll
        for (int j = 2; j < 8; ++j) xa1[j] = 0.0f;
    }
    split8p(xa0, X[0], X[1]);
    split8p(xa1, X[2], X[3]);
}

// prep: zero sums; transposed frag tables + bias/wout quads (same as round 4)
__global__ __launch_bounds__(256) void prep_kernel(
    const float* __restrict__ w1, const float* __restrict__ w2,
    const float* __restrict__ wimg, const float* __restrict__ wsc,
    const float* __restrict__ b1, const float* __restrict__ b2,
    const float* __restrict__ bimg, const float* __restrict__ bsc,
    const float* __restrict__ wout, char* __restrict__ wsb) {
    int t = blockIdx.x * 256 + threadIdx.x;
    float* sums = (float*)wsb;
    if (t < 16000) { sums[t] = 0.0f; return; }
    t -= 16000;
    if (t < 40960) {  // W1^T frags: A[u][k] = W1[k][u]
        int l = t >> 11, r = t & 2047;
        int tm = r >> 10, ks = (r >> 9) & 1, lane = (r >> 3) & 63, j = r & 7;
        int k = 16 * ks + 8 * (lane >> 5) + j;
        int u = 32 * tm + (lane & 31);
        short hh, ll;
        split1(w1[l * 2048 + k * 64 + u], hh, ll);
        char* base = wsb + WB + l * LSTR2 + (tm * 2 + ks) * 2048 + 2 * (lane * 8 + j);
        *(short*)base = hh;
        *(short*)(base + 1024) = ll;
        return;
    }
    t -= 40960;
    if (t < 40960) {  // W2^T frags: A[w][u] = W2[u][w]
        int l = t >> 11, r = t & 2047;
        int ks = r >> 9, lane = (r >> 3) & 63, j = r & 7;
        int u = 16 * ks + 8 * (lane >> 5) + j;
        int w = lane & 31;
        short hh, ll;
        split1(w2[l * 2048 + u * 32 + w], hh, ll);
        char* base = wsb + WB + l * LSTR2 + 8192 + ks * 2048 + 2 * (lane * 8 + j);
        *(short*)base = hh;
        *(short*)(base + 1024) = ll;
        return;
    }
    t -= 40960;
    if (t < 1280) {  // b1 quads [l][tm][h5][reg]
        int l = t >> 6, r = t & 63;
        int tm = r >> 5, h5 = (r >> 4) & 1, reg = r & 15;
        *(float*)(wsb + WB + l * LSTR2 + 16384 + tm * 128 + h5 * 64 + reg * 4) =
            b1[l * 64 + 32 * tm + WOFFi(h5, reg)];
        return;
    }
    t -= 1280;
    if (t < 640) {  // b2 quads [l][h5][reg]
        int l = t >> 5, r = t & 31;
        int h5 = r >> 4, reg = r & 15;
        *(float*)(wsb + WB + l * LSTR2 + 16640 + h5 * 64 + reg * 4) =
            b2[l * 32 + WOFFi(h5, reg)];
        return;
    }
    t -= 640;
    if (t < 1024) {  // wimg^T frags (d padded 26->32)
        int ks = t >> 9, lane = (t >> 3) & 63, j = t & 7;
        int d = 16 * ks + 8 * (lane >> 5) + j, w = lane & 31;
        float v = (d < 26) ? wimg[d * 32 + w] : 0.0f;
        short hh, ll;
        split1(v, hh, ll);
        char* base = wsb + OFF_WI + ks * 2048 + 2 * (lane * 8 + j);
        *(short*)base = hh;
        *(short*)(base + 1024) = ll;
        return;
    }
    t -= 1024;
    if (t < 1024) {  // wsc^T frags (d padded 24->32)
        int ks = t >> 9, lane = (t >> 3) & 63, j = t & 7;
        int d = 16 * ks + 8 * (lane >> 5) + j, w = lane & 31;
        float v = (d < 24) ? wsc[d * 32 + w] : 0.0f;
        short hh, ll;
        split1(v, hh, ll);
        char* base = wsb + OFF_WS + ks * 2048 + 2 * (lane * 8 + j);
        *(short*)base = hh;
        *(short*)(base + 1024) = ll;
        return;
    }
    t -= 1024;
    if (t < 32) {  // bimg quads
        int h5 = t >> 4, reg = t & 15;
        *(float*)(wsb + OFF_BIQ + h5 * 64 + reg * 4) = bimg[WOFFi(h5, reg)];
        return;
    }
    t -= 32;
    if (t < 32) {  // bsc quads
        int h5 = t >> 4, reg = t & 15;
        *(float*)(wsb + OFF_BSQ + h5 * 64 + reg * 4) = bsc[WOFFi(h5, reg)];
        return;
    }
    t -= 32;
    if (t < 64) {  // wout quads [h5][reg][2]
        int h5 = t >> 5, r = t & 31, reg = r >> 1, comp = r & 1;
        *(float*)(wsb + OFF_WOQ + h5 * 128 + reg * 8 + comp * 4) =
            wout[WOFFi(h5, reg) * 2 + comp];
        return;
    }
}

// pass A: input proj -> mlp20 (2 tiles/wave) -> segment-sum
__global__ __launch_bounds__(128, 3) void pass_a(
    const float* __restrict__ md, const float* __restrict__ iobs,
    const float* __restrict__ sig, const char* __restrict__ wsb,
    const int* __restrict__ ids, float* __restrict__ sums) {
    int lane = threadIdx.x & 63, wv = threadIdx.x >> 6;
    int h5 = lane >> 5;
    int gw = blockIdx.x * 2 + wv;
    int R = gw * 64;
    if (R >= N_ROWS) return;
    int row0 = R + (lane & 31), row1 = row0 + 32;

    bf16x8 X0[4], X1[4];
    load_xfrags(md, iobs, sig, row0, h5, X0);
    load_xfrags(md, iobs, sig, row1, h5, X1);

    float h0[16], h1[16];
    input_proj32_x2(X0, X1, wsb, OFF_WI, OFF_BIQ, h0, h1, lane, h5);
    mlp20_x2(h0, h1, wsb, lane, h5);

#pragma unroll
    for (int tile = 0; tile < 2; ++tile) {
        float* h = tile ? h1 : h0;
        int tb = R + tile * 32;
        int rowt = tile ? row1 : row0;
        int id0 = ids[tb];
        bool uni = (id0 == ids[tb + 31]);
        if (uni) {
#pragma unroll
            for (int m = 1; m < 32; m <<= 1) {
#pragma unroll
                for (int i = 0; i < 16; ++i) h[i] += __shfl_xor(h[i], m, 64);
            }
            if ((lane & 31) == 0) {
#pragma unroll
                for (int i = 0; i < 16; ++i)
                    atomicAdd(&sums[id0 * 32 + WOFFi(h5, i)], h[i]);
            }
        } else {
            int id = ids[rowt];
#pragma unroll
            for (int i = 0; i < 16; ++i)
                atomicAdd(&sums[id * 32 + WOFFi(h5, i)], h[i]);
        }
    }
}

__global__ __launch_bounds__(256) void normalize_kernel(float* __restrict__ sums,
                                                        const int* __restrict__ cnts) {
    int t = blockIdx.x * 256 + threadIdx.x;
    if (t < NIMG * WIDTH) {
        int img = t >> 5;
        float cc = (float)max(cnts[img], 1);
        sums[t] = sums[t] / cc;
    }
}

// pass B: input proj + pooled -> mlp20 (2 tiles/wave) -> head -> sample
__global__ __launch_bounds__(128, 3) void pass_b(
    const float* __restrict__ md, const char* __restrict__ wsb,
    const float* __restrict__ bout, const int* __restrict__ ids,
    const float* __restrict__ pooled, float* __restrict__ out) {
    int lane = threadIdx.x & 63, wv = threadIdx.x >> 6;
    int h5 = lane >> 5;
    int gw = blockIdx.x * 2 + wv;
    int R = gw * 64;
    if (R >= N_ROWS) return;
    int row0 = R + (lane & 31), row1 = row0 + 32;

    bf16x8 X0[4], X1[4];
    load_xfrags(md, nullptr, nullptr, row0, h5, X0);
    load_xfrags(md, nullptr, nullptr, row1, h5, X1);

    float h0[16], h1[16];
    input_proj32_x2(X0, X1, wsb, OFF_WS, OFF_BSQ, h0, h1, lane, h5);

    // add pooled[id][w] per tile (pooled row layout matches WOFF quads)
#pragma unroll
    for (int tile = 0; tile < 2; ++tile) {
        float* h = tile ? h1 : h0;
        int idp = ids[tile ? row1 : row0];
#pragma unroll
        for (int a = 0; a < 4; ++a) {
            f32x4 q = *(const f32x4*)(pooled + idp * 32 + 8 * a + 4 * h5);
#pragma unroll
            for (int i = 0; i < 4; ++i) h[4 * a + i] += q[i];
        }
    }

    mlp20_x2(h0, h1, wsb, lane, h5);

    // head weights (shared by both tiles)
    f32x4 wq[8];
    {
        const char* wp = wsb + OFF_WOQ + (uint32_t)(h5 * 128);
#pragma unroll
        for (int r = 0; r < 8; ++r) wq[r] = *(const f32x4*)(wp + 16 * r);
    }
#pragma unroll
    for (int tile = 0; tile < 2; ++tile) {
        const float* h = tile ? h1 : h0;
        int row = tile ? row1 : row0;
        float p0 = 0.0f, p1 = 0.0f;
#pragma unroll
        for (int r = 0; r < 8; ++r) {
            p0 = fmaf(h[2 * r], wq[r][0], p0);
            p1 = fmaf(h[2 * r], wq[r][1], p1);
            p0 = fmaf(h[2 * r + 1], wq[r][2], p0);
            p1 = fmaf(h[2 * r + 1], wq[r][3], p1);
        }
        p0 += __shfl_xor(p0, 32, 64);
        p1 += __shfl_xor(p1, 32, 64);
        float loc = p0 + bout[0];
        float pb = p1 + bout[1];
        float scale = fmaxf(pb, 0.0f) + log1pf(expf(-fabsf(pb))) + 1e-12f;
        float lsg = logf(scale);

        float kp = 0.0f;
        float* zrow = out + (size_t)row * MC + h5 * 16;
#pragma unroll 4
        for (int s4 = 0; s4 < 4; ++s4) {
            f32x4 zv;
#pragma unroll
            for (int jj = 0; jj < 4; ++jj) {
                int tt = h5 * 16 + s4 * 4 + jj;
                uint32_t j = (uint32_t)(tt * N_ROWS) + (uint32_t)row;
                float n = bits_to_normal(tf_bits(j));
                float z = fmaf(scale, n, loc);
                zv[jj] = z;
                kp += fmaf(-0.5f, n * n, fabsf(z));
            }
            *(f32x4*)(zrow + s4 * 4) = zv;
        }
        kp += __shfl_xor(kp, 32, 64);
        if (h5 == 0) {
            out[(size_t)N_ROWS * MC + row] =
                0.01f * (kp * (1.0f / 32.0f) - lsg - 0.91893853320467274f + 0.69314718055994531f);
        }
    }
}

extern "C" void kernel_launch(void* const* d_in, const int* in_sizes, int n_in,
                              void* d_out, int out_size, void* d_ws, size_t ws_size,
                              hipStream_t stream) {
    const float* md   = (const float*)d_in[0];
    const float* iobs = (const float*)d_in[1];
    const float* sig  = (const float*)d_in[2];
    const float* wimg = (const float*)d_in[3];
    const float* bimg = (const float*)d_in[4];
    const float* wsc  = (const float*)d_in[5];
    const float* bsc  = (const float*)d_in[6];
    const float* w1   = (const float*)d_in[7];
    const float* b1   = (const float*)d_in[8];
    const float* w2   = (const float*)d_in[9];
    const float* b2   = (const float*)d_in[10];
    const float* wout = (const float*)d_in[11];
    const float* bout = (const float*)d_in[12];
    const int* ids    = (const int*)d_in[13];
    const int* cnts   = (const int*)d_in[14];
    float* out = (float*)d_out;
    char* wsb = (char*)d_ws;
    float* sums = (float*)wsb;

    // 3125 wave-tiles of 64 rows; 2 waves/block -> 1563 blocks (tail wave idles)
    const int nblk = 1563;
    prep_kernel<<<399, 256, 0, stream>>>(w1, w2, wimg, wsc, b1, b2, bimg, bsc, wout, wsb);
    pass_a<<<nblk, 128, 0, stream>>>(md, iobs, sig, wsb, ids, sums);
    normalize_kernel<<<(NIMG * WIDTH + 255) / 256, 256, 0, stream>>>(sums, cnts);
    pass_b<<<nblk, 128, 0, stream>>>(md, wsb, bout, ids, sums, out);
}